// Round 1
// 538.131 us; speedup vs baseline: 1.0396x; 1.0396x over previous
//
#include <hip/hip_runtime.h>
#include <hip/hip_bf16.h>
#include <cstddef>
#include <cstdint>

#define TOKENS 4096
#define DMODEL 1024
#define DFFN   2048
#define NEXP   8
#define MAXT_E 72                 // max 128-row expert m-tiles
#define MT_SH  (TOKENS / 128)     // 32 shared m-tiles
#define MT_ALL (MT_SH + MAXT_E)   // 104

typedef __attribute__((ext_vector_type(8))) __bf16 bf16x8;
typedef __attribute__((ext_vector_type(4))) float f4_t;
typedef __attribute__((ext_vector_type(4))) unsigned short us4;

__device__ __forceinline__ unsigned short f2bf(float f) {
  union { float f; unsigned int u; } v; v.f = f;
  unsigned int r = v.u + 0x7FFFu + ((v.u >> 16) & 1u);
  return (unsigned short)(r >> 16);
}

__device__ __forceinline__ void glds16(const void* g, void* l) {
  __builtin_amdgcn_global_load_lds((const __attribute__((address_space(1))) void*)g,
                                   (__attribute__((address_space(3))) void*)l, 16, 0, 0);
}

// ---------------- fused pre-pass: x fp32->bf16 + 6 weight transposes ----------------
#define CONV_BLKS 2048
__global__ __launch_bounds__(256) void prepass_kernel(
    const float* __restrict__ x, unsigned short* __restrict__ xb,
    const float* __restrict__ swg, unsigned short* __restrict__ swgT,
    const float* __restrict__ swu, unsigned short* __restrict__ swuT,
    const float* __restrict__ swd, unsigned short* __restrict__ swdT,
    const float* __restrict__ ewg, unsigned short* __restrict__ ewgT,
    const float* __restrict__ ewu, unsigned short* __restrict__ ewuT,
    const float* __restrict__ ewd, unsigned short* __restrict__ ewdT) {
  __shared__ float sF[128][65];
  int b = blockIdx.x, tid = threadIdx.x;
  if (b < CONV_BLKS) {
    int i = b * 2048 + tid * 8;
    float4 a = *(const float4*)&x[i];
    float4 c = *(const float4*)&x[i + 4];
    union { unsigned short u[8]; uint4 v; } p;
    p.u[0] = f2bf(a.x); p.u[1] = f2bf(a.y); p.u[2] = f2bf(a.z); p.u[3] = f2bf(a.w);
    p.u[4] = f2bf(c.x); p.u[5] = f2bf(c.y); p.u[6] = f2bf(c.z); p.u[7] = f2bf(c.w);
    *(uint4*)&xb[i] = p.v;
    return;
  }
  b -= CONV_BLKS;
  const float* src; unsigned short* dst; int R, C;
  if (b < 256)       { src = swg; dst = swgT; R = 1024; C = 2048; }
  else if (b < 512)  { b -= 256; src = swu; dst = swuT; R = 1024; C = 2048; }
  else if (b < 768)  { b -= 512; src = swd; dst = swdT; R = 2048; C = 1024; }
  else if (b < 2816) { b -= 768; int e = b >> 8; b &= 255;
                       src = ewg + (size_t)e * (DMODEL * DFFN); dst = ewgT + (size_t)e * (DMODEL * DFFN);
                       R = 1024; C = 2048; }
  else if (b < 4864) { b -= 2816; int e = b >> 8; b &= 255;
                       src = ewu + (size_t)e * (DMODEL * DFFN); dst = ewuT + (size_t)e * (DMODEL * DFFN);
                       R = 1024; C = 2048; }
  else               { b -= 4864; int e = b >> 8; b &= 255;
                       src = ewd + (size_t)e * (DFFN * DMODEL); dst = ewdT + (size_t)e * (DFFN * DMODEL);
                       R = 2048; C = 1024; }
  int ntc = C >> 6;
  int tr = b / ntc, tc = b - tr * ntc;
  int r0 = tr * 128, c0 = tc * 64;
#pragma unroll
  for (int it = 0; it < 8; ++it) {
    int r = it * 16 + (tid >> 4);
    int c = (tid & 15) * 4;
    float4 v = *(const float4*)&src[(size_t)(r0 + r) * C + c0 + c];
    sF[r][c + 0] = v.x; sF[r][c + 1] = v.y; sF[r][c + 2] = v.z; sF[r][c + 3] = v.w;
  }
  __syncthreads();
  // write: 16 consecutive lanes write one contiguous 256B column run (coalesced)
#pragma unroll
  for (int pass = 0; pass < 4; ++pass) {
    int cc = pass * 16 + (tid >> 4);
    int r8 = (tid & 15) * 8;
    union { unsigned short u[8]; uint4 v; } p;
#pragma unroll
    for (int i = 0; i < 8; ++i) p.u[i] = f2bf(sF[r8 + i][cc]);
    *(uint4*)(dst + (size_t)(c0 + cc) * R + r0 + r8) = p.v;
  }
}

// ---------------- router: 1 wave per token ----------------
__global__ __launch_bounds__(256) void router_kernel(
    const float* __restrict__ x, const float* __restrict__ rw,
    int* __restrict__ topi, float* __restrict__ topw,
    int* __restrict__ c_part, float* __restrict__ p_part) {
  __shared__ float sW[DMODEL * NEXP];
  __shared__ int sc[NEXP];
  __shared__ float sp[NEXP];
  for (int i = threadIdx.x; i < DMODEL * NEXP; i += 256) sW[i] = rw[i];
  if (threadIdx.x < NEXP) { sc[threadIdx.x] = 0; sp[threadIdx.x] = 0.f; }
  __syncthreads();
  int wave = threadIdx.x >> 6, lane = threadIdx.x & 63;
  int t = blockIdx.x * 4 + wave;
  const float* xr = x + (size_t)t * DMODEL;
  float acc[NEXP];
#pragma unroll
  for (int e = 0; e < NEXP; ++e) acc[e] = 0.f;
  for (int i = 0; i < DMODEL / 64; ++i) {
    int d = lane + 64 * i;
    float xv = xr[d];
#pragma unroll
    for (int e = 0; e < NEXP; ++e) acc[e] += xv * sW[d * NEXP + e];
  }
#pragma unroll
  for (int off = 32; off > 0; off >>= 1) {
#pragma unroll
    for (int e = 0; e < NEXP; ++e) acc[e] += __shfl_down(acc[e], off, 64);
  }
  if (lane == 0) {
    float m = acc[0];
#pragma unroll
    for (int e = 1; e < NEXP; ++e) m = fmaxf(m, acc[e]);
    float s = 0.f, p[NEXP];
#pragma unroll
    for (int e = 0; e < NEXP; ++e) { p[e] = expf(acc[e] - m); s += p[e]; }
    float inv = 1.f / s;
    int i1 = 0;
#pragma unroll
    for (int e = 1; e < NEXP; ++e) if (acc[e] > acc[i1]) i1 = e;
    int i2 = (i1 == 0) ? 1 : 0;
#pragma unroll
    for (int e = 0; e < NEXP; ++e) if (e != i1 && acc[e] > acc[i2]) i2 = e;
    float w1 = 1.f / (1.f + expf(acc[i2] - acc[i1]));
    topi[2 * t] = i1; topi[2 * t + 1] = i2;
    topw[2 * t] = w1; topw[2 * t + 1] = 1.f - w1;
    atomicAdd(&sc[i1], 1); atomicAdd(&sc[i2], 1);
#pragma unroll
    for (int e = 0; e < NEXP; ++e) atomicAdd(&sp[e], p[e] * inv);
  }
  __syncthreads();
  if (threadIdx.x < NEXP) {
    c_part[blockIdx.x * NEXP + threadIdx.x] = sc[threadIdx.x];
    p_part[blockIdx.x * NEXP + threadIdx.x] = sp[threadIdx.x];
  }
}

// ---------------- scan: offsets + aux + tile list ----------------
__global__ void scan_aux_kernel(const int* __restrict__ c_part,
                                const float* __restrict__ p_part,
                                int* __restrict__ counts, int* __restrict__ offsets,
                                int* __restrict__ te, int* __restrict__ tb,
                                int* __restrict__ ntl,
                                float* __restrict__ aux_out) {
  __shared__ int sc[32][NEXP];
  __shared__ float sp[32][NEXP];
  __shared__ int fc[NEXP];
  __shared__ float fp[NEXP];
  int e = threadIdx.x & 7, g = threadIdx.x >> 3;
  int cs = 0; float ps = 0.f;
  for (int b = g; b < TOKENS / 4; b += 32) { cs += c_part[b * NEXP + e]; ps += p_part[b * NEXP + e]; }
  sc[g][e] = cs; sp[g][e] = ps;
  __syncthreads();
  if (threadIdx.x < NEXP) {
    int c = 0; float p = 0.f;
    for (int gg = 0; gg < 32; ++gg) { c += sc[gg][threadIdx.x]; p += sp[gg][threadIdx.x]; }
    fc[threadIdx.x] = c; fp[threadIdx.x] = p;
    counts[threadIdx.x] = c;
  }
  __syncthreads();
  if (threadIdx.x == 0) {
    int off = 0; float aux = 0.f; int idx = 0;
    for (int ee = 0; ee < NEXP; ++ee) {
      offsets[ee] = off;
      int nt = (fc[ee] + 127) >> 7;
      for (int t = 0; t < nt; ++t) { te[idx] = ee; tb[idx] = t * 128; ++idx; }
      off += fc[ee];
      aux += (float)fc[ee] * fp[ee];
    }
    ntl[0] = idx;
    aux_out[0] = (float)NEXP * aux / ((float)TOKENS * (float)TOKENS);
  }
}

// ---------------- dispatch ----------------
__global__ void dispatch_kernel(const int* __restrict__ topi, const float* __restrict__ topw,
                                const int* __restrict__ offsets, int* __restrict__ fill,
                                int* __restrict__ token_list, float* __restrict__ weight_list,
                                int* __restrict__ slot_idx) {
  int t = blockIdx.x * 256 + threadIdx.x;
  if (t >= TOKENS) return;
#pragma unroll
  for (int k = 0; k < 2; ++k) {
    int e = topi[2 * t + k]; float w = topw[2 * t + k];
    int pos = atomicAdd(&fill[e], 1);
    int idx = offsets[e] + pos;
    token_list[idx] = t;
    weight_list[idx] = w;
    slot_idx[2 * t + k] = idx;
  }
}

// ---------------- G1: pipelined + swizzled ----------------
// LDS per buffer (shorts): pair-A [128 rows][64] (cols 0-31 Ag-panel, 32-63 Au-panel) = 8192,
// B [64 rowpairs][64] (tokens 2r | 2r+1) = 4096.  Swizzle: chunk ^= (row & 7), chunk=16B.
// Pipeline: 32-K panels, stage(next) -> compute(cur) -> syncthreads (vmcnt(0) pre-covered).
__global__ __launch_bounds__(512, 4) void g1_kernel(
    const unsigned short* __restrict__ xb,
    const unsigned short* __restrict__ swgT, const unsigned short* __restrict__ swuT,
    const unsigned short* __restrict__ ewgT, const unsigned short* __restrict__ ewuT,
    const int* __restrict__ counts, const int* __restrict__ offsets,
    const int* __restrict__ te, const int* __restrict__ tb, const int* __restrict__ ntl,
    const int* __restrict__ token_list,
    unsigned short* __restrict__ hbuf) {
  // XCD-chunked remap (grid 1664 = 8 * 208, bijective)
  int bid = blockIdx.x;
  int b = (bid & 7) * (MT_ALL * 16 / 8) + (bid >> 3);
  int ff_blk = b & 15;
  int mt = b >> 4;
  int f0 = ff_blk * 128;
  const unsigned short *wgT, *wuT;
  int h_base, tl_base, nvalid;
  bool shared_e;
  if (mt < MT_SH) {
    shared_e = true; wgT = swgT; wuT = swuT;
    h_base = mt * 128; tl_base = 0; nvalid = 128;
  } else {
    int em = mt - MT_SH;
    if (em >= ntl[0]) return;
    int e = te[em], lb = tb[em];
    shared_e = false;
    nvalid = min(128, counts[e] - lb);
    tl_base = offsets[e] + lb;
    h_base = TOKENS + tl_base;
    wgT = ewgT + (size_t)e * (DMODEL * DFFN);
    wuT = ewuT + (size_t)e * (DMODEL * DFFN);
  }
  __shared__ unsigned short sm[2 * 12288];
  __shared__ int s_tok[128];
  int tid = threadIdx.x;
  if (tid < 128) {
    s_tok[tid] = shared_e ? (h_base + tid) : token_list[tl_base + min(tid, nvalid - 1)];
  }
  __syncthreads();

  // staging source pointers (pre-swizzled global source, linear LDS dest)
  int rlo = tid >> 3;                       // write-row (A: rows rlo / 64+rlo; B: pair-row rlo)
  int c8 = (tid & 7) ^ (rlo & 7);           // logical chunk held by this thread's slot
  int kc = (c8 & 3) * 8;                    // k-offset in shorts
  const unsigned short* wsel = (c8 < 4) ? wgT : wuT;
  const unsigned short* pA0 = wsel + (size_t)(f0 + rlo) * DMODEL + kc;
  const unsigned short* pA1 = wsel + (size_t)(f0 + 64 + rlo) * DMODEL + kc;
  const unsigned short* pB0 = xb + (size_t)s_tok[rlo * 2 + (c8 >> 2)] * DMODEL + kc;

  int wv = tid >> 6, lane = tid & 63;
  int wm = wv & 1, wn = wv >> 1;
  int lm = lane & 15, quad = lane >> 4;

  // swizzled read offsets (shorts), loop-invariant
  int rA = wm * 64 + lm;
  int stg = quad ^ (lm & 7);
  int aG = rA * 64 + stg * 8;               // Ag_i at aG + i*1024
  int aU = rA * 64 + (stg ^ 4) * 8;         // Au_i at aU + i*1024
  int prB = wn * 16 + (lm >> 1);
  int stb = ((lm & 1) * 4 + quad) ^ ((lm >> 1) & 7);
  int aB = 8192 + prB * 64 + stb * 8;       // B_j at aB + j*512

  f4_t accg[4][2], accu[4][2];
#pragma unroll
  for (int i = 0; i < 4; ++i)
#pragma unroll
    for (int j = 0; j < 2; ++j)
#pragma unroll
      for (int r = 0; r < 4; ++r) { accg[i][j][r] = 0.f; accu[i][j][r] = 0.f; }

  auto stage = [&](int sb, int k) {
    glds16(pA0 + k, &sm[sb + tid * 8]);
    glds16(pA1 + k, &sm[sb + 4096 + tid * 8]);
    glds16(pB0 + k, &sm[sb + 8192 + tid * 8]);
  };
  auto compute = [&](int sb) {
    bf16x8 b0 = *(const bf16x8*)&sm[sb + aB];
    bf16x8 b1 = *(const bf16x8*)&sm[sb + aB + 512];
#pragma unroll
    for (int i = 0; i < 4; ++i) {
      bf16x8 ag = *(const bf16x8*)&sm[sb + aG + i * 1024];
      bf16x8 au = *(const bf16x8*)&sm[sb + aU + i * 1024];
      accg[i][0] = __builtin_amdgcn_mfma_f32_16x16x32_bf16(ag, b0, accg[i][0], 0, 0, 0);
      accg[i][1] = __builtin_amdgcn_mfma_f32_16x16x32_bf16(ag, b1, accg[i][1], 0, 0, 0);
      accu[i][0] = __builtin_amdgcn_mfma_f32_16x16x32_bf16(au, b0, accu[i][0], 0, 0, 0);
      accu[i][1] = __builtin_amdgcn_mfma_f32_16x16x32_bf16(au, b1, accu[i][1], 0, 0, 0);
    }
  };

  stage(0, 0);
  __syncthreads();
  for (int k0 = 0; k0 < DMODEL; k0 += 64) {
    stage(12288, k0 + 32);                  // always in range (k0 <= 960)
    compute(0);
    __syncthreads();
    if (k0 + 64 < DMODEL) stage(0, k0 + 64);
    compute(12288);
    __syncthreads();
  }

#pragma unroll
  for (int j = 0; j < 2; ++j) {
    int tok = wn * 32 + j * 16 + lm;
    if (tok < nvalid) {
      unsigned short* hrow = hbuf + (size_t)(h_base + tok) * DFFN + f0 + wm * 64 + quad * 4;
#pragma unroll
      for (int i = 0; i < 4; ++i) {
        us4 h4;
#pragma unroll
        for (int r = 0; r < 4; ++r) {
          float g = accg[i][j][r], u = accu[i][j][r];
          h4[r] = f2bf(g / (1.f + __expf(-g)) * u);
        }
        *(us4*)(hrow + i * 16) = h4;
      }
    }
  }
}

// ---------------- G2: pipelined + swizzled down-proj ----------------
// LDS per buffer (shorts): pair tile [128 rows][64] (cols 0-31 A=hbuf panel, 32-63 B=wdT panel) = 8192.
__global__ __launch_bounds__(512, 4) void g2_kernel(
    const unsigned short* __restrict__ hbuf,
    const unsigned short* __restrict__ swdT, const unsigned short* __restrict__ ewdT,
    const int* __restrict__ counts, const int* __restrict__ offsets,
    const int* __restrict__ te, const int* __restrict__ tb, const int* __restrict__ ntl,
    const float* __restrict__ weight_list,
    float* __restrict__ out, float* __restrict__ eres) {
  // XCD-chunked remap (grid 832 = 8 * 104, bijective)
  int bid = blockIdx.x;
  int b = (bid & 7) * (MT_ALL * 8 / 8) + (bid >> 3);
  int nt_blk = b & 7;
  int mt = b >> 3;
  int d0 = nt_blk * 128;
  const unsigned short* wdT;
  int h_base, tl_base, nvalid;
  bool shared_e;
  if (mt < MT_SH) {
    shared_e = true; wdT = swdT;
    h_base = mt * 128; tl_base = 0; nvalid = 128;
  } else {
    int em = mt - MT_SH;
    if (em >= ntl[0]) return;
    int e = te[em], lb = tb[em];
    shared_e = false;
    nvalid = min(128, counts[e] - lb);
    tl_base = offsets[e] + lb;
    h_base = TOKENS + tl_base;
    wdT = ewdT + (size_t)e * (DFFN * DMODEL);
  }
  __shared__ unsigned short sm[2 * 8192];
  __shared__ float s_w[128];
  int tid = threadIdx.x;
  if (tid < 128) {
    s_w[tid] = shared_e ? 1.f : weight_list[tl_base + min(tid, nvalid - 1)];
  }

  int rlo = tid >> 3;
  int c8 = (tid & 7) ^ (rlo & 7);
  int kc = (c8 & 3) * 8;
  const unsigned short* p0 = (c8 < 4)
      ? hbuf + (size_t)(h_base + rlo) * DFFN + kc
      : wdT + (size_t)(d0 + rlo) * DFFN + kc;
  const unsigned short* p1 = (c8 < 4)
      ? hbuf + (size_t)(h_base + 64 + rlo) * DFFN + kc
      : wdT + (size_t)(d0 + 64 + rlo) * DFFN + kc;

  int wv = tid >> 6, lane = tid & 63;
  int wm = wv & 1, wn = wv >> 1;
  int lm = lane & 15, quad = lane >> 4;

  int rA = wm * 64 + lm;
  int aA = rA * 64 + (quad ^ (lm & 7)) * 8;            // A_i at aA + i*1024
  int rB = wn * 32 + lm;
  int aB = rB * 64 + (((4 + quad)) ^ (lm & 7)) * 8;    // B_j at aB + j*1024

  f4_t acc[4][2];
#pragma unroll
  for (int i = 0; i < 4; ++i)
#pragma unroll
    for (int j = 0; j < 2; ++j)
#pragma unroll
      for (int r = 0; r < 4; ++r) acc[i][j][r] = 0.f;

  auto stage = [&](int sb, int k) {
    glds16(p0 + k, &sm[sb + tid * 8]);
    glds16(p1 + k, &sm[sb + 4096 + tid * 8]);
  };
  auto compute = [&](int sb) {
    bf16x8 b0 = *(const bf16x8*)&sm[sb + aB];
    bf16x8 b1 = *(const bf16x8*)&sm[sb + aB + 1024];
#pragma unroll
    for (int i = 0; i < 4; ++i) {
      bf16x8 a = *(const bf16x8*)&sm[sb + aA + i * 1024];
      acc[i][0] = __builtin_amdgcn_mfma_f32_16x16x32_bf16(a, b0, acc[i][0], 0, 0, 0);
      acc[i][1] = __builtin_amdgcn_mfma_f32_16x16x32_bf16(a, b1, acc[i][1], 0, 0, 0);
    }
  };

  stage(0, 0);
  __syncthreads();
  for (int k0 = 0; k0 < DFFN; k0 += 64) {
    stage(8192, k0 + 32);                   // always in range (k0 <= 1984)
    compute(0);
    __syncthreads();
    if (k0 + 64 < DFFN) stage(0, k0 + 64);
    compute(8192);
    __syncthreads();
  }

#pragma unroll
  for (int i = 0; i < 4; ++i)
#pragma unroll
    for (int r = 0; r < 4; ++r) {
      int rw = wm * 64 + i * 16 + quad * 4 + r;
      if (rw < nvalid) {
        float w = s_w[rw];
        if (shared_e) {
          float* orow = out + (size_t)(h_base + rw) * DMODEL + d0 + wn * 32 + lm;
          orow[0] = acc[i][0][r];
          orow[16] = acc[i][1][r];
        } else {
          float* erow = eres + (size_t)(tl_base + rw) * DMODEL + d0 + wn * 32 + lm;
          erow[0] = w * acc[i][0][r];
          erow[16] = w * acc[i][1][r];
        }
      }
    }
}

// ---------------- combine ----------------
__global__ __launch_bounds__(256) void combine_kernel(float* __restrict__ out,
                                                      const float* __restrict__ eres,
                                                      const int* __restrict__ slot_idx) {
  int t = blockIdx.x;
  int s1 = slot_idx[2 * t], s2 = slot_idx[2 * t + 1];
  int d = threadIdx.x * 4;
  float4 o = *(float4*)&out[(size_t)t * DMODEL + d];
  float4 a = *(const float4*)&eres[(size_t)s1 * DMODEL + d];
  float4 b = *(const float4*)&eres[(size_t)s2 * DMODEL + d];
  o.x += a.x + b.x; o.y += a.y + b.y; o.z += a.z + b.z; o.w += a.w + b.w;
  *(float4*)&out[(size_t)t * DMODEL + d] = o;
}

extern "C" void kernel_launch(void* const* d_in, const int* in_sizes, int n_in,
                              void* d_out, int out_size, void* d_ws, size_t ws_size,
                              hipStream_t stream) {
  const float* x   = (const float*)d_in[0];
  const float* swg = (const float*)d_in[1];
  const float* swu = (const float*)d_in[2];
  const float* swd = (const float*)d_in[3];
  const float* ewg = (const float*)d_in[4];
  const float* ewu = (const float*)d_in[5];
  const float* ewd = (const float*)d_in[6];
  const float* rw  = (const float*)d_in[7];
  float* out = (float*)d_out;

  char* ws = (char*)d_ws;
  const size_t MB = 1048576;
  int*   fill     = (int*)(ws + 0);
  int*   counts   = (int*)(ws + 64);
  int*   offsets  = (int*)(ws + 128);
  int*   ntl      = (int*)(ws + 192);
  int*   te       = (int*)(ws + 256);
  int*   tb       = (int*)(ws + 1024);
  int*   topi     = (int*)(ws + 65536);
  float* topw     = (float*)(ws + 98304);
  int*   c_part   = (int*)(ws + 131072);
  float* p_part   = (float*)(ws + 163840);
  int*   tok_list = (int*)(ws + 196608);
  float* w_list   = (float*)(ws + 229376);
  int*   slot_idx = (int*)(ws + 262144);
  unsigned short* xb   = (unsigned short*)(ws + 1 * MB);
  unsigned short* swgT = (unsigned short*)(ws + 16 * MB);
  unsigned short* swuT = (unsigned short*)(ws + 20 * MB);
  unsigned short* swdT = (unsigned short*)(ws + 24 * MB);
  unsigned short* ewgT = (unsigned short*)(ws + 28 * MB);
  unsigned short* ewuT = (unsigned short*)(ws + 60 * MB);
  unsigned short* ewdT = (unsigned short*)(ws + 92 * MB);
  float*          eres = (float*)(ws + 28 * MB);
  unsigned short* hbuf = (unsigned short*)(ws + 124 * MB);

  hipMemsetAsync(ws, 0, 32, stream);  // fill[]

  prepass_kernel<<<CONV_BLKS + 6912, 256, 0, stream>>>(
      x, xb, swg, swgT, swu, swuT, swd, swdT, ewg, ewgT, ewu, ewuT, ewd, ewdT);
  router_kernel<<<TOKENS / 4, 256, 0, stream>>>(x, rw, topi, topw, c_part, p_part);
  scan_aux_kernel<<<1, 256, 0, stream>>>(c_part, p_part, counts, offsets, te, tb, ntl,
                                         out + (size_t)TOKENS * DMODEL);
  dispatch_kernel<<<TOKENS / 256, 256, 0, stream>>>(topi, topw, offsets, fill,
                                                    tok_list, w_list, slot_idx);

  g1_kernel<<<MT_ALL * 16, 512, 0, stream>>>(xb, swgT, swuT, ewgT, ewuT,
                                             counts, offsets, te, tb, ntl, tok_list, hbuf);
  g2_kernel<<<MT_ALL * 8, 512, 0, stream>>>(hbuf, swdT, ewdT,
                                            counts, offsets, te, tb, ntl, w_list, out, eres);
  combine_kernel<<<TOKENS, 256, 0, stream>>>(out, eres, slot_idx);
}

// Round 2
// 526.554 us; speedup vs baseline: 1.0625x; 1.0220x over previous
//
#include <hip/hip_runtime.h>
#include <hip/hip_bf16.h>
#include <cstddef>
#include <cstdint>

#define TOKENS 4096
#define DMODEL 1024
#define DFFN   2048
#define NEXP   8
#define MAXT_E 72                 // max 128-row expert m-tiles
#define MT_SH  (TOKENS / 128)     // 32 shared m-tiles
#define MT_ALL (MT_SH + MAXT_E)   // 104

typedef __attribute__((ext_vector_type(8))) __bf16 bf16x8;
typedef __attribute__((ext_vector_type(4))) float f4_t;
typedef __attribute__((ext_vector_type(4))) unsigned short us4;

__device__ __forceinline__ unsigned short f2bf(float f) {
  union { float f; unsigned int u; } v; v.f = f;
  unsigned int r = v.u + 0x7FFFu + ((v.u >> 16) & 1u);
  return (unsigned short)(r >> 16);
}

__device__ __forceinline__ void glds16(const void* g, void* l) {
  __builtin_amdgcn_global_load_lds((const __attribute__((address_space(1))) void*)g,
                                   (__attribute__((address_space(3))) void*)l, 16, 0, 0);
}

// ---------------- fused pre-pass: x fp32->bf16 + 6 weight transposes ----------------
#define CONV_BLKS 2048
__global__ __launch_bounds__(256) void prepass_kernel(
    const float* __restrict__ x, unsigned short* __restrict__ xb,
    const float* __restrict__ swg, unsigned short* __restrict__ swgT,
    const float* __restrict__ swu, unsigned short* __restrict__ swuT,
    const float* __restrict__ swd, unsigned short* __restrict__ swdT,
    const float* __restrict__ ewg, unsigned short* __restrict__ ewgT,
    const float* __restrict__ ewu, unsigned short* __restrict__ ewuT,
    const float* __restrict__ ewd, unsigned short* __restrict__ ewdT) {
  __shared__ float sF[128][65];
  int b = blockIdx.x, tid = threadIdx.x;
  if (b < CONV_BLKS) {
    int i = b * 2048 + tid * 8;
    float4 a = *(const float4*)&x[i];
    float4 c = *(const float4*)&x[i + 4];
    union { unsigned short u[8]; uint4 v; } p;
    p.u[0] = f2bf(a.x); p.u[1] = f2bf(a.y); p.u[2] = f2bf(a.z); p.u[3] = f2bf(a.w);
    p.u[4] = f2bf(c.x); p.u[5] = f2bf(c.y); p.u[6] = f2bf(c.z); p.u[7] = f2bf(c.w);
    *(uint4*)&xb[i] = p.v;
    return;
  }
  b -= CONV_BLKS;
  const float* src; unsigned short* dst; int R, C;
  if (b < 256)       { src = swg; dst = swgT; R = 1024; C = 2048; }
  else if (b < 512)  { b -= 256; src = swu; dst = swuT; R = 1024; C = 2048; }
  else if (b < 768)  { b -= 512; src = swd; dst = swdT; R = 2048; C = 1024; }
  else if (b < 2816) { b -= 768; int e = b >> 8; b &= 255;
                       src = ewg + (size_t)e * (DMODEL * DFFN); dst = ewgT + (size_t)e * (DMODEL * DFFN);
                       R = 1024; C = 2048; }
  else if (b < 4864) { b -= 2816; int e = b >> 8; b &= 255;
                       src = ewu + (size_t)e * (DMODEL * DFFN); dst = ewuT + (size_t)e * (DMODEL * DFFN);
                       R = 1024; C = 2048; }
  else               { b -= 4864; int e = b >> 8; b &= 255;
                       src = ewd + (size_t)e * (DFFN * DMODEL); dst = ewdT + (size_t)e * (DFFN * DMODEL);
                       R = 2048; C = 1024; }
  int ntc = C >> 6;
  int tr = b / ntc, tc = b - tr * ntc;
  int r0 = tr * 128, c0 = tc * 64;
#pragma unroll
  for (int it = 0; it < 8; ++it) {
    int r = it * 16 + (tid >> 4);
    int c = (tid & 15) * 4;
    float4 v = *(const float4*)&src[(size_t)(r0 + r) * C + c0 + c];
    sF[r][c + 0] = v.x; sF[r][c + 1] = v.y; sF[r][c + 2] = v.z; sF[r][c + 3] = v.w;
  }
  __syncthreads();
#pragma unroll
  for (int pass = 0; pass < 4; ++pass) {
    int cc = pass * 16 + (tid >> 4);
    int r8 = (tid & 15) * 8;
    union { unsigned short u[8]; uint4 v; } p;
#pragma unroll
    for (int i = 0; i < 8; ++i) p.u[i] = f2bf(sF[r8 + i][cc]);
    *(uint4*)(dst + (size_t)(c0 + cc) * R + r0 + r8) = p.v;
  }
}

// ---------------- router: 1 wave per token ----------------
__global__ __launch_bounds__(256) void router_kernel(
    const float* __restrict__ x, const float* __restrict__ rw,
    int* __restrict__ topi, float* __restrict__ topw,
    int* __restrict__ c_part, float* __restrict__ p_part) {
  __shared__ float sW[DMODEL * NEXP];
  __shared__ int sc[NEXP];
  __shared__ float sp[NEXP];
  for (int i = threadIdx.x; i < DMODEL * NEXP; i += 256) sW[i] = rw[i];
  if (threadIdx.x < NEXP) { sc[threadIdx.x] = 0; sp[threadIdx.x] = 0.f; }
  __syncthreads();
  int wave = threadIdx.x >> 6, lane = threadIdx.x & 63;
  int t = blockIdx.x * 4 + wave;
  const float* xr = x + (size_t)t * DMODEL;
  float acc[NEXP];
#pragma unroll
  for (int e = 0; e < NEXP; ++e) acc[e] = 0.f;
  for (int i = 0; i < DMODEL / 64; ++i) {
    int d = lane + 64 * i;
    float xv = xr[d];
#pragma unroll
    for (int e = 0; e < NEXP; ++e) acc[e] += xv * sW[d * NEXP + e];
  }
#pragma unroll
  for (int off = 32; off > 0; off >>= 1) {
#pragma unroll
    for (int e = 0; e < NEXP; ++e) acc[e] += __shfl_down(acc[e], off, 64);
  }
  if (lane == 0) {
    float m = acc[0];
#pragma unroll
    for (int e = 1; e < NEXP; ++e) m = fmaxf(m, acc[e]);
    float s = 0.f, p[NEXP];
#pragma unroll
    for (int e = 0; e < NEXP; ++e) { p[e] = expf(acc[e] - m); s += p[e]; }
    float inv = 1.f / s;
    int i1 = 0;
#pragma unroll
    for (int e = 1; e < NEXP; ++e) if (acc[e] > acc[i1]) i1 = e;
    int i2 = (i1 == 0) ? 1 : 0;
#pragma unroll
    for (int e = 0; e < NEXP; ++e) if (e != i1 && acc[e] > acc[i2]) i2 = e;
    float w1 = 1.f / (1.f + expf(acc[i2] - acc[i1]));
    topi[2 * t] = i1; topi[2 * t + 1] = i2;
    topw[2 * t] = w1; topw[2 * t + 1] = 1.f - w1;
    atomicAdd(&sc[i1], 1); atomicAdd(&sc[i2], 1);
#pragma unroll
    for (int e = 0; e < NEXP; ++e) atomicAdd(&sp[e], p[e] * inv);
  }
  __syncthreads();
  if (threadIdx.x < NEXP) {
    c_part[blockIdx.x * NEXP + threadIdx.x] = sc[threadIdx.x];
    p_part[blockIdx.x * NEXP + threadIdx.x] = sp[threadIdx.x];
  }
}

// ---------------- scan: offsets + aux + tile list ----------------
__global__ void scan_aux_kernel(const int* __restrict__ c_part,
                                const float* __restrict__ p_part,
                                int* __restrict__ counts, int* __restrict__ offsets,
                                int* __restrict__ te, int* __restrict__ tb,
                                int* __restrict__ ntl,
                                float* __restrict__ aux_out) {
  __shared__ int sc[32][NEXP];
  __shared__ float sp[32][NEXP];
  __shared__ int fc[NEXP];
  __shared__ float fp[NEXP];
  int e = threadIdx.x & 7, g = threadIdx.x >> 3;
  int cs = 0; float ps = 0.f;
  for (int b = g; b < TOKENS / 4; b += 32) { cs += c_part[b * NEXP + e]; ps += p_part[b * NEXP + e]; }
  sc[g][e] = cs; sp[g][e] = ps;
  __syncthreads();
  if (threadIdx.x < NEXP) {
    int c = 0; float p = 0.f;
    for (int gg = 0; gg < 32; ++gg) { c += sc[gg][threadIdx.x]; p += sp[gg][threadIdx.x]; }
    fc[threadIdx.x] = c; fp[threadIdx.x] = p;
    counts[threadIdx.x] = c;
  }
  __syncthreads();
  if (threadIdx.x == 0) {
    int off = 0; float aux = 0.f; int idx = 0;
    for (int ee = 0; ee < NEXP; ++ee) {
      offsets[ee] = off;
      int nt = (fc[ee] + 127) >> 7;
      for (int t = 0; t < nt; ++t) { te[idx] = ee; tb[idx] = t * 128; ++idx; }
      off += fc[ee];
      aux += (float)fc[ee] * fp[ee];
    }
    ntl[0] = idx;
    aux_out[0] = (float)NEXP * aux / ((float)TOKENS * (float)TOKENS);
  }
}

// ---------------- dispatch ----------------
__global__ void dispatch_kernel(const int* __restrict__ topi, const float* __restrict__ topw,
                                const int* __restrict__ offsets, int* __restrict__ fill,
                                int* __restrict__ token_list, float* __restrict__ weight_list,
                                int* __restrict__ slot_idx) {
  int t = blockIdx.x * 256 + threadIdx.x;
  if (t >= TOKENS) return;
#pragma unroll
  for (int k = 0; k < 2; ++k) {
    int e = topi[2 * t + k]; float w = topw[2 * t + k];
    int pos = atomicAdd(&fill[e], 1);
    int idx = offsets[e] + pos;
    token_list[idx] = t;
    weight_list[idx] = w;
    slot_idx[2 * t + k] = idx;
  }
}

// ---------------- G1: 3-buffer counted-vmcnt pipeline + swizzled LDS ----------------
// per-buffer (shorts): pair-A [128r][64] (chunks 0-3 Ag, 4-7 Au) = 8192, B [64 pair-rows][64] = 4096.
// phase p: stage(buf[(p+1)%3], k=(p+1)*32); vmcnt(3); s_barrier; MFMA(buf[p%3]).
// counted vmcnt => staged loads get 2 compute phases + barrier of latency cover; never drained to 0 in loop.
__global__ __launch_bounds__(512, 4) void g1_kernel(
    const unsigned short* __restrict__ xb,
    const unsigned short* __restrict__ swgT, const unsigned short* __restrict__ swuT,
    const unsigned short* __restrict__ ewgT, const unsigned short* __restrict__ ewuT,
    const int* __restrict__ counts, const int* __restrict__ offsets,
    const int* __restrict__ te, const int* __restrict__ tb, const int* __restrict__ ntl,
    const int* __restrict__ token_list,
    unsigned short* __restrict__ hbuf) {
  // XCD chunking, mt-fast within chunk: weight-pair panel (0.5 MB) stays L2-hot across 13 blocks
  int bid = blockIdx.x;
  int chunk = bid & 7, i = bid >> 3;        // chunk == XCD (bid%8 round-robin)
  int mt = chunk * 13 + (i % 13);           // 104/8 = 13 mt per chunk
  int ff_blk = i / 13;
  int f0 = ff_blk * 128;
  const unsigned short *wgT, *wuT;
  int h_base, tl_base, nvalid;
  bool shared_e;
  if (mt < MT_SH) {
    shared_e = true; wgT = swgT; wuT = swuT;
    h_base = mt * 128; tl_base = 0; nvalid = 128;
  } else {
    int em = mt - MT_SH;
    if (em >= ntl[0]) return;
    int e = te[em], lb = tb[em];
    shared_e = false;
    nvalid = min(128, counts[e] - lb);
    tl_base = offsets[e] + lb;
    h_base = TOKENS + tl_base;
    wgT = ewgT + (size_t)e * (DMODEL * DFFN);
    wuT = ewuT + (size_t)e * (DMODEL * DFFN);
  }
  __shared__ unsigned short sm[3 * 12288];
  __shared__ int s_tok[128];
  int tid = threadIdx.x;
  if (tid < 128) {
    s_tok[tid] = shared_e ? (h_base + tid) : token_list[tl_base + min(tid, nvalid - 1)];
  }
  __syncthreads();

  // staging source pointers (pre-swizzled global source, linear LDS dest)
  int rlo = tid >> 3;
  int c8 = (tid & 7) ^ (rlo & 7);
  int kc = (c8 & 3) * 8;
  const unsigned short* wsel = (c8 < 4) ? wgT : wuT;
  const unsigned short* pA0 = wsel + (size_t)(f0 + rlo) * DMODEL + kc;
  const unsigned short* pA1 = wsel + (size_t)(f0 + 64 + rlo) * DMODEL + kc;
  const unsigned short* pB0 = xb + (size_t)s_tok[rlo * 2 + (c8 >> 2)] * DMODEL + kc;

  int wv = tid >> 6, lane = tid & 63;
  int wm = wv & 1, wn = wv >> 1;
  int lm = lane & 15, quad = lane >> 4;

  int rA = wm * 64 + lm;
  int stg = quad ^ (lm & 7);
  int aG = rA * 64 + stg * 8;
  int aU = rA * 64 + (stg ^ 4) * 8;
  int prB = wn * 16 + (lm >> 1);
  int stb = ((lm & 1) * 4 + quad) ^ ((lm >> 1) & 7);
  int aB = 8192 + prB * 64 + stb * 8;

  f4_t accg[4][2], accu[4][2];
#pragma unroll
  for (int ii = 0; ii < 4; ++ii)
#pragma unroll
    for (int j = 0; j < 2; ++j)
#pragma unroll
      for (int r = 0; r < 4; ++r) { accg[ii][j][r] = 0.f; accu[ii][j][r] = 0.f; }

  auto stage = [&](int sb, int k) {
    glds16(pA0 + k, &sm[sb + tid * 8]);
    glds16(pA1 + k, &sm[sb + 4096 + tid * 8]);
    glds16(pB0 + k, &sm[sb + 8192 + tid * 8]);
  };
  auto compute = [&](int sb) {
    bf16x8 b0 = *(const bf16x8*)&sm[sb + aB];
    bf16x8 b1 = *(const bf16x8*)&sm[sb + aB + 512];
#pragma unroll
    for (int ii = 0; ii < 4; ++ii) {
      bf16x8 ag = *(const bf16x8*)&sm[sb + aG + ii * 1024];
      bf16x8 au = *(const bf16x8*)&sm[sb + aU + ii * 1024];
      accg[ii][0] = __builtin_amdgcn_mfma_f32_16x16x32_bf16(ag, b0, accg[ii][0], 0, 0, 0);
      accg[ii][1] = __builtin_amdgcn_mfma_f32_16x16x32_bf16(ag, b1, accg[ii][1], 0, 0, 0);
      accu[ii][0] = __builtin_amdgcn_mfma_f32_16x16x32_bf16(au, b0, accu[ii][0], 0, 0, 0);
      accu[ii][1] = __builtin_amdgcn_mfma_f32_16x16x32_bf16(au, b1, accu[ii][1], 0, 0, 0);
    }
  };

#define G1_PHASE(CB, NB, KK)                               \
  stage(NB, KK);                                           \
  asm volatile("s_waitcnt vmcnt(3)" ::: "memory");         \
  __builtin_amdgcn_s_barrier();                            \
  asm volatile("" ::: "memory");                           \
  __builtin_amdgcn_s_setprio(1);                           \
  compute(CB);                                             \
  __builtin_amdgcn_s_setprio(0);

  stage(0, 0);
  int k = 0;
#pragma unroll 1
  for (int g = 0; g < 10; ++g) {
    G1_PHASE(0, 12288, k + 32);
    G1_PHASE(12288, 24576, k + 64);
    G1_PHASE(24576, 0, k + 96);
    k += 96;
  }
  G1_PHASE(0, 12288, 992);                 // phase 30
  asm volatile("s_waitcnt vmcnt(0)" ::: "memory");
  __builtin_amdgcn_s_barrier();
  asm volatile("" ::: "memory");
  __builtin_amdgcn_s_setprio(1);
  compute(12288);                          // phase 31
  __builtin_amdgcn_s_setprio(0);
#undef G1_PHASE

#pragma unroll
  for (int j = 0; j < 2; ++j) {
    int tok = wn * 32 + j * 16 + lm;
    if (tok < nvalid) {
      unsigned short* hrow = hbuf + (size_t)(h_base + tok) * DFFN + f0 + wm * 64 + quad * 4;
#pragma unroll
      for (int ii = 0; ii < 4; ++ii) {
        us4 h4;
#pragma unroll
        for (int r = 0; r < 4; ++r) {
          float g2 = accg[ii][j][r], u = accu[ii][j][r];
          h4[r] = f2bf(g2 / (1.f + __expf(-g2)) * u);
        }
        *(us4*)(hrow + ii * 16) = h4;
      }
    }
  }
}

// ---------------- G2: 3-buffer counted-vmcnt down-proj ----------------
// per-buffer (shorts): pair tile [128r][64] (chunks 0-3 A=hbuf, 4-7 B=wdT) = 8192.
__global__ __launch_bounds__(512, 4) void g2_kernel(
    const unsigned short* __restrict__ hbuf,
    const unsigned short* __restrict__ swdT, const unsigned short* __restrict__ ewdT,
    const int* __restrict__ counts, const int* __restrict__ offsets,
    const int* __restrict__ te, const int* __restrict__ tb, const int* __restrict__ ntl,
    const float* __restrict__ weight_list,
    float* __restrict__ out, float* __restrict__ eres) {
  // XCD chunking, d-fast within chunk (A-tile hot across 8 d-blocks; weight set ~4MB/mt L2-resident)
  int bid = blockIdx.x;
  int b = (bid & 7) * (MT_ALL * 8 / 8) + (bid >> 3);
  int nt_blk = b & 7;
  int mt = b >> 3;
  int d0 = nt_blk * 128;
  const unsigned short* wdT;
  int h_base, tl_base, nvalid;
  bool shared_e;
  if (mt < MT_SH) {
    shared_e = true; wdT = swdT;
    h_base = mt * 128; tl_base = 0; nvalid = 128;
  } else {
    int em = mt - MT_SH;
    if (em >= ntl[0]) return;
    int e = te[em], lb = tb[em];
    shared_e = false;
    nvalid = min(128, counts[e] - lb);
    tl_base = offsets[e] + lb;
    h_base = TOKENS + tl_base;
    wdT = ewdT + (size_t)e * (DFFN * DMODEL);
  }
  __shared__ unsigned short sm[3 * 8192];
  __shared__ float s_w[128];
  int tid = threadIdx.x;
  if (tid < 128) {
    s_w[tid] = shared_e ? 1.f : weight_list[tl_base + min(tid, nvalid - 1)];
  }

  int rlo = tid >> 3;
  int c8 = (tid & 7) ^ (rlo & 7);
  int kc = (c8 & 3) * 8;
  const unsigned short* p0 = (c8 < 4)
      ? hbuf + (size_t)(h_base + rlo) * DFFN + kc
      : wdT + (size_t)(d0 + rlo) * DFFN + kc;
  const unsigned short* p1 = (c8 < 4)
      ? hbuf + (size_t)(h_base + 64 + rlo) * DFFN + kc
      : wdT + (size_t)(d0 + 64 + rlo) * DFFN + kc;

  int wv = tid >> 6, lane = tid & 63;
  int wm = wv & 1, wn = wv >> 1;
  int lm = lane & 15, quad = lane >> 4;

  int rA = wm * 64 + lm;
  int aA = rA * 64 + (quad ^ (lm & 7)) * 8;
  int rB = wn * 32 + lm;
  int aB = rB * 64 + (((4 + quad)) ^ (lm & 7)) * 8;

  f4_t acc[4][2];
#pragma unroll
  for (int ii = 0; ii < 4; ++ii)
#pragma unroll
    for (int j = 0; j < 2; ++j)
#pragma unroll
      for (int r = 0; r < 4; ++r) acc[ii][j][r] = 0.f;

  auto stage = [&](int sb, int k) {
    glds16(p0 + k, &sm[sb + tid * 8]);
    glds16(p1 + k, &sm[sb + 4096 + tid * 8]);
  };
  auto compute = [&](int sb) {
    bf16x8 b0 = *(const bf16x8*)&sm[sb + aB];
    bf16x8 b1 = *(const bf16x8*)&sm[sb + aB + 1024];
#pragma unroll
    for (int ii = 0; ii < 4; ++ii) {
      bf16x8 a = *(const bf16x8*)&sm[sb + aA + ii * 1024];
      acc[ii][0] = __builtin_amdgcn_mfma_f32_16x16x32_bf16(a, b0, acc[ii][0], 0, 0, 0);
      acc[ii][1] = __builtin_amdgcn_mfma_f32_16x16x32_bf16(a, b1, acc[ii][1], 0, 0, 0);
    }
  };

#define G2_PHASE(CB, NB, KK)                               \
  stage(NB, KK);                                           \
  asm volatile("s_waitcnt vmcnt(2)" ::: "memory");         \
  __builtin_amdgcn_s_barrier();                            \
  asm volatile("" ::: "memory");                           \
  __builtin_amdgcn_s_setprio(1);                           \
  compute(CB);                                             \
  __builtin_amdgcn_s_setprio(0);

  stage(0, 0);
  int k = 0;
#pragma unroll 1
  for (int g = 0; g < 21; ++g) {           // phases 0..62
    G2_PHASE(0, 8192, k + 32);
    G2_PHASE(8192, 16384, k + 64);
    G2_PHASE(16384, 0, k + 96);
    k += 96;
  }
  asm volatile("s_waitcnt vmcnt(0)" ::: "memory");
  __builtin_amdgcn_s_barrier();
  asm volatile("" ::: "memory");
  __builtin_amdgcn_s_setprio(1);
  compute(0);                              // phase 63
  __builtin_amdgcn_s_setprio(0);
#undef G2_PHASE

#pragma unroll
  for (int ii = 0; ii < 4; ++ii)
#pragma unroll
    for (int r = 0; r < 4; ++r) {
      int rw = wm * 64 + ii * 16 + quad * 4 + r;
      if (rw < nvalid) {
        float w = s_w[rw];
        if (shared_e) {
          float* orow = out + (size_t)(h_base + rw) * DMODEL + d0 + wn * 32 + lm;
          orow[0] = acc[ii][0][r];
          orow[16] = acc[ii][1][r];
        } else {
          float* erow = eres + (size_t)(tl_base + rw) * DMODEL + d0 + wn * 32 + lm;
          erow[0] = w * acc[ii][0][r];
          erow[16] = w * acc[ii][1][r];
        }
      }
    }
}

// ---------------- combine ----------------
__global__ __launch_bounds__(256) void combine_kernel(float* __restrict__ out,
                                                      const float* __restrict__ eres,
                                                      const int* __restrict__ slot_idx) {
  int t = blockIdx.x;
  int s1 = slot_idx[2 * t], s2 = slot_idx[2 * t + 1];
  int d = threadIdx.x * 4;
  float4 o = *(float4*)&out[(size_t)t * DMODEL + d];
  float4 a = *(const float4*)&eres[(size_t)s1 * DMODEL + d];
  float4 b = *(const float4*)&eres[(size_t)s2 * DMODEL + d];
  o.x += a.x + b.x; o.y += a.y + b.y; o.z += a.z + b.z; o.w += a.w + b.w;
  *(float4*)&out[(size_t)t * DMODEL + d] = o;
}

extern "C" void kernel_launch(void* const* d_in, const int* in_sizes, int n_in,
                              void* d_out, int out_size, void* d_ws, size_t ws_size,
                              hipStream_t stream) {
  const float* x   = (const float*)d_in[0];
  const float* swg = (const float*)d_in[1];
  const float* swu = (const float*)d_in[2];
  const float* swd = (const float*)d_in[3];
  const float* ewg = (const float*)d_in[4];
  const float* ewu = (const float*)d_in[5];
  const float* ewd = (const float*)d_in[6];
  const float* rw  = (const float*)d_in[7];
  float* out = (float*)d_out;

  char* ws = (char*)d_ws;
  const size_t MB = 1048576;
  int*   fill     = (int*)(ws + 0);
  int*   counts   = (int*)(ws + 64);
  int*   offsets  = (int*)(ws + 128);
  int*   ntl      = (int*)(ws + 192);
  int*   te       = (int*)(ws + 256);
  int*   tb       = (int*)(ws + 1024);
  int*   topi     = (int*)(ws + 65536);
  float* topw     = (float*)(ws + 98304);
  int*   c_part   = (int*)(ws + 131072);
  float* p_part   = (float*)(ws + 163840);
  int*   tok_list = (int*)(ws + 196608);
  float* w_list   = (float*)(ws + 229376);
  int*   slot_idx = (int*)(ws + 262144);
  unsigned short* xb   = (unsigned short*)(ws + 1 * MB);
  unsigned short* swgT = (unsigned short*)(ws + 16 * MB);
  unsigned short* swuT = (unsigned short*)(ws + 20 * MB);
  unsigned short* swdT = (unsigned short*)(ws + 24 * MB);
  unsigned short* ewgT = (unsigned short*)(ws + 28 * MB);
  unsigned short* ewuT = (unsigned short*)(ws + 60 * MB);
  unsigned short* ewdT = (unsigned short*)(ws + 92 * MB);
  float*          eres = (float*)(ws + 28 * MB);
  unsigned short* hbuf = (unsigned short*)(ws + 124 * MB);

  hipMemsetAsync(ws, 0, 32, stream);  // fill[]

  prepass_kernel<<<CONV_BLKS + 6912, 256, 0, stream>>>(
      x, xb, swg, swgT, swu, swuT, swd, swdT, ewg, ewgT, ewu, ewuT, ewd, ewdT);
  router_kernel<<<TOKENS / 4, 256, 0, stream>>>(x, rw, topi, topw, c_part, p_part);
  scan_aux_kernel<<<1, 256, 0, stream>>>(c_part, p_part, counts, offsets, te, tb, ntl,
                                         out + (size_t)TOKENS * DMODEL);
  dispatch_kernel<<<TOKENS / 256, 256, 0, stream>>>(topi, topw, offsets, fill,
                                                    tok_list, w_list, slot_idx);

  g1_kernel<<<MT_ALL * 16, 512, 0, stream>>>(xb, swgT, swuT, ewgT, ewuT,
                                             counts, offsets, te, tb, ntl, tok_list, hbuf);
  g2_kernel<<<MT_ALL * 8, 512, 0, stream>>>(hbuf, swdT, ewdT,
                                            counts, offsets, te, tb, ntl, w_list, out, eres);
  combine_kernel<<<TOKENS, 256, 0, stream>>>(out, eres, slot_idx);
}

// Round 3
// 526.454 us; speedup vs baseline: 1.0627x; 1.0002x over previous
//
#include <hip/hip_runtime.h>
#include <hip/hip_bf16.h>
#include <cstddef>
#include <cstdint>

#define TOKENS 4096
#define DMODEL 1024
#define DFFN   2048
#define NEXP   8
#define MAXT_E 72                 // max 128-row expert m-tiles
#define MT_SH  (TOKENS / 128)     // 32 shared m-tiles
#define MT_ALL (MT_SH + MAXT_E)   // 104

typedef __attribute__((ext_vector_type(8))) __bf16 bf16x8;
typedef __attribute__((ext_vector_type(4))) float f4_t;
typedef __attribute__((ext_vector_type(4))) unsigned short us4;

__device__ __forceinline__ unsigned short f2bf(float f) {
  union { float f; unsigned int u; } v; v.f = f;
  unsigned int r = v.u + 0x7FFFu + ((v.u >> 16) & 1u);
  return (unsigned short)(r >> 16);
}

__device__ __forceinline__ void glds16(const void* g, void* l) {
  __builtin_amdgcn_global_load_lds((const __attribute__((address_space(1))) void*)g,
                                   (__attribute__((address_space(3))) void*)l, 16, 0, 0);
}

#define MFMA16(a, b, c) __builtin_amdgcn_mfma_f32_16x16x32_bf16(a, b, c, 0, 0, 0)

// ---------------- fused pre-pass: x fp32->bf16 + 6 weight transposes ----------------
#define CONV_BLKS 2048
__global__ __launch_bounds__(256) void prepass_kernel(
    const float* __restrict__ x, unsigned short* __restrict__ xb,
    const float* __restrict__ swg, unsigned short* __restrict__ swgT,
    const float* __restrict__ swu, unsigned short* __restrict__ swuT,
    const float* __restrict__ swd, unsigned short* __restrict__ swdT,
    const float* __restrict__ ewg, unsigned short* __restrict__ ewgT,
    const float* __restrict__ ewu, unsigned short* __restrict__ ewuT,
    const float* __restrict__ ewd, unsigned short* __restrict__ ewdT) {
  __shared__ float sF[128][65];
  int b = blockIdx.x, tid = threadIdx.x;
  if (b < CONV_BLKS) {
    int i = b * 2048 + tid * 8;
    float4 a = *(const float4*)&x[i];
    float4 c = *(const float4*)&x[i + 4];
    union { unsigned short u[8]; uint4 v; } p;
    p.u[0] = f2bf(a.x); p.u[1] = f2bf(a.y); p.u[2] = f2bf(a.z); p.u[3] = f2bf(a.w);
    p.u[4] = f2bf(c.x); p.u[5] = f2bf(c.y); p.u[6] = f2bf(c.z); p.u[7] = f2bf(c.w);
    *(uint4*)&xb[i] = p.v;
    return;
  }
  b -= CONV_BLKS;
  const float* src; unsigned short* dst; int R, C;
  if (b < 256)       { src = swg; dst = swgT; R = 1024; C = 2048; }
  else if (b < 512)  { b -= 256; src = swu; dst = swuT; R = 1024; C = 2048; }
  else if (b < 768)  { b -= 512; src = swd; dst = swdT; R = 2048; C = 1024; }
  else if (b < 2816) { b -= 768; int e = b >> 8; b &= 255;
                       src = ewg + (size_t)e * (DMODEL * DFFN); dst = ewgT + (size_t)e * (DMODEL * DFFN);
                       R = 1024; C = 2048; }
  else if (b < 4864) { b -= 2816; int e = b >> 8; b &= 255;
                       src = ewu + (size_t)e * (DMODEL * DFFN); dst = ewuT + (size_t)e * (DMODEL * DFFN);
                       R = 1024; C = 2048; }
  else               { b -= 4864; int e = b >> 8; b &= 255;
                       src = ewd + (size_t)e * (DFFN * DMODEL); dst = ewdT + (size_t)e * (DFFN * DMODEL);
                       R = 2048; C = 1024; }
  int ntc = C >> 6;
  int tr = b / ntc, tc = b - tr * ntc;
  int r0 = tr * 128, c0 = tc * 64;
#pragma unroll
  for (int it = 0; it < 8; ++it) {
    int r = it * 16 + (tid >> 4);
    int c = (tid & 15) * 4;
    float4 v = *(const float4*)&src[(size_t)(r0 + r) * C + c0 + c];
    sF[r][c + 0] = v.x; sF[r][c + 1] = v.y; sF[r][c + 2] = v.z; sF[r][c + 3] = v.w;
  }
  __syncthreads();
#pragma unroll
  for (int pass = 0; pass < 4; ++pass) {
    int cc = pass * 16 + (tid >> 4);
    int r8 = (tid & 15) * 8;
    union { unsigned short u[8]; uint4 v; } p;
#pragma unroll
    for (int i = 0; i < 8; ++i) p.u[i] = f2bf(sF[r8 + i][cc]);
    *(uint4*)(dst + (size_t)(c0 + cc) * R + r0 + r8) = p.v;
  }
}

// ---------------- router: 1 wave per token ----------------
__global__ __launch_bounds__(256) void router_kernel(
    const float* __restrict__ x, const float* __restrict__ rw,
    int* __restrict__ topi, float* __restrict__ topw,
    int* __restrict__ c_part, float* __restrict__ p_part) {
  __shared__ float sW[DMODEL * NEXP];
  __shared__ int sc[NEXP];
  __shared__ float sp[NEXP];
  for (int i = threadIdx.x; i < DMODEL * NEXP; i += 256) sW[i] = rw[i];
  if (threadIdx.x < NEXP) { sc[threadIdx.x] = 0; sp[threadIdx.x] = 0.f; }
  __syncthreads();
  int wave = threadIdx.x >> 6, lane = threadIdx.x & 63;
  int t = blockIdx.x * 4 + wave;
  const float* xr = x + (size_t)t * DMODEL;
  float acc[NEXP];
#pragma unroll
  for (int e = 0; e < NEXP; ++e) acc[e] = 0.f;
  for (int i = 0; i < DMODEL / 64; ++i) {
    int d = lane + 64 * i;
    float xv = xr[d];
#pragma unroll
    for (int e = 0; e < NEXP; ++e) acc[e] += xv * sW[d * NEXP + e];
  }
#pragma unroll
  for (int off = 32; off > 0; off >>= 1) {
#pragma unroll
    for (int e = 0; e < NEXP; ++e) acc[e] += __shfl_down(acc[e], off, 64);
  }
  if (lane == 0) {
    float m = acc[0];
#pragma unroll
    for (int e = 1; e < NEXP; ++e) m = fmaxf(m, acc[e]);
    float s = 0.f, p[NEXP];
#pragma unroll
    for (int e = 0; e < NEXP; ++e) { p[e] = expf(acc[e] - m); s += p[e]; }
    float inv = 1.f / s;
    int i1 = 0;
#pragma unroll
    for (int e = 1; e < NEXP; ++e) if (acc[e] > acc[i1]) i1 = e;
    int i2 = (i1 == 0) ? 1 : 0;
#pragma unroll
    for (int e = 0; e < NEXP; ++e) if (e != i1 && acc[e] > acc[i2]) i2 = e;
    float w1 = 1.f / (1.f + expf(acc[i2] - acc[i1]));
    topi[2 * t] = i1; topi[2 * t + 1] = i2;
    topw[2 * t] = w1; topw[2 * t + 1] = 1.f - w1;
    atomicAdd(&sc[i1], 1); atomicAdd(&sc[i2], 1);
#pragma unroll
    for (int e = 0; e < NEXP; ++e) atomicAdd(&sp[e], p[e] * inv);
  }
  __syncthreads();
  if (threadIdx.x < NEXP) {
    c_part[blockIdx.x * NEXP + threadIdx.x] = sc[threadIdx.x];
    p_part[blockIdx.x * NEXP + threadIdx.x] = sp[threadIdx.x];
  }
}

// ---------------- scan: offsets + aux + tile list ----------------
__global__ void scan_aux_kernel(const int* __restrict__ c_part,
                                const float* __restrict__ p_part,
                                int* __restrict__ counts, int* __restrict__ offsets,
                                int* __restrict__ te, int* __restrict__ tb,
                                int* __restrict__ ntl,
                                float* __restrict__ aux_out) {
  __shared__ int sc[32][NEXP];
  __shared__ float sp[32][NEXP];
  __shared__ int fc[NEXP];
  __shared__ float fp[NEXP];
  int e = threadIdx.x & 7, g = threadIdx.x >> 3;
  int cs = 0; float ps = 0.f;
  for (int b = g; b < TOKENS / 4; b += 32) { cs += c_part[b * NEXP + e]; ps += p_part[b * NEXP + e]; }
  sc[g][e] = cs; sp[g][e] = ps;
  __syncthreads();
  if (threadIdx.x < NEXP) {
    int c = 0; float p = 0.f;
    for (int gg = 0; gg < 32; ++gg) { c += sc[gg][threadIdx.x]; p += sp[gg][threadIdx.x]; }
    fc[threadIdx.x] = c; fp[threadIdx.x] = p;
    counts[threadIdx.x] = c;
  }
  __syncthreads();
  if (threadIdx.x == 0) {
    int off = 0; float aux = 0.f; int idx = 0;
    for (int ee = 0; ee < NEXP; ++ee) {
      offsets[ee] = off;
      int nt = (fc[ee] + 127) >> 7;
      for (int t = 0; t < nt; ++t) { te[idx] = ee; tb[idx] = t * 128; ++idx; }
      off += fc[ee];
      aux += (float)fc[ee] * fp[ee];
    }
    ntl[0] = idx;
    aux_out[0] = (float)NEXP * aux / ((float)TOKENS * (float)TOKENS);
  }
}

// ---------------- dispatch ----------------
__global__ void dispatch_kernel(const int* __restrict__ topi, const float* __restrict__ topw,
                                const int* __restrict__ offsets, int* __restrict__ fill,
                                int* __restrict__ token_list, float* __restrict__ weight_list,
                                int* __restrict__ slot_idx) {
  int t = blockIdx.x * 256 + threadIdx.x;
  if (t >= TOKENS) return;
#pragma unroll
  for (int k = 0; k < 2; ++k) {
    int e = topi[2 * t + k]; float w = topw[2 * t + k];
    int pos = atomicAdd(&fill[e], 1);
    int idx = offsets[e] + pos;
    token_list[idx] = t;
    weight_list[idx] = w;
    slot_idx[2 * t + k] = idx;
  }
}

// ---------------- G1: 4-wave 64x64 wave-tiles, 3-buffer counted-vmcnt pipeline ----------------
// per-buffer (shorts): pair-A [128r][64] (chunks 0-3 Ag, 4-7 Au) = 8192, B [64 pair-rows][64] = 4096.
// wave (wm,wn): 64 ffn x 64 tok computing BOTH g and u -> 12 ds_read_b128 per 32 MFMA.
__global__ __launch_bounds__(256, 2) void g1_kernel(
    const unsigned short* __restrict__ xb,
    const unsigned short* __restrict__ swgT, const unsigned short* __restrict__ swuT,
    const unsigned short* __restrict__ ewgT, const unsigned short* __restrict__ ewuT,
    const int* __restrict__ counts, const int* __restrict__ offsets,
    const int* __restrict__ te, const int* __restrict__ tb, const int* __restrict__ ntl,
    const int* __restrict__ token_list,
    unsigned short* __restrict__ hbuf) {
  // XCD chunking, mt-fast within chunk (measured best FETCH in r2)
  int bid = blockIdx.x;
  int chunk = bid & 7, i = bid >> 3;
  int mt = chunk * 13 + (i % 13);
  int ff_blk = i / 13;
  int f0 = ff_blk * 128;
  const unsigned short *wgT, *wuT;
  int h_base, tl_base, nvalid;
  bool shared_e;
  if (mt < MT_SH) {
    shared_e = true; wgT = swgT; wuT = swuT;
    h_base = mt * 128; tl_base = 0; nvalid = 128;
  } else {
    int em = mt - MT_SH;
    if (em >= ntl[0]) return;
    int e = te[em], lb = tb[em];
    shared_e = false;
    nvalid = min(128, counts[e] - lb);
    tl_base = offsets[e] + lb;
    h_base = TOKENS + tl_base;
    wgT = ewgT + (size_t)e * (DMODEL * DFFN);
    wuT = ewuT + (size_t)e * (DMODEL * DFFN);
  }
  __shared__ unsigned short sm[3 * 12288];
  __shared__ int s_tok[128];
  int tid = threadIdx.x;
  if (tid < 128) {
    s_tok[tid] = shared_e ? (h_base + tid) : token_list[tl_base + min(tid, nvalid - 1)];
  }
  __syncthreads();

  // staging: thread covers 4 A slots (rows rlo+32q) and 2 B slots; pre-swizzled global source
  int rlo = tid >> 3;                      // 0..31
  int c8 = (tid & 7) ^ (rlo & 7);          // logical chunk at this thread's linear LDS slot
  int kc = (c8 & 3) * 8;
  const unsigned short* wsel = (c8 < 4) ? wgT : wuT;
  const unsigned short* pA  = wsel + (size_t)(f0 + rlo) * DMODEL + kc;
  const unsigned short* pB0 = xb + (size_t)s_tok[rlo * 2 + (c8 >> 2)] * DMODEL + kc;
  const unsigned short* pB1 = xb + (size_t)s_tok[64 + rlo * 2 + (c8 >> 2)] * DMODEL + kc;

  int wv = tid >> 6, lane = tid & 63;      // wv 0..3
  int wm = wv & 1, wn = wv >> 1;           // wm: ffn half, wn: token half
  int lm = lane & 15, quad = lane >> 4;

  int rA = wm * 64 + lm;
  int stg = quad ^ (lm & 7);
  int aG = rA * 64 + stg * 8;              // Ag frag i at aG + i*1024
  int aU = rA * 64 + (stg ^ 4) * 8;        // Au frag i at aU + i*1024
  int prB = wn * 32 + (lm >> 1);
  int stb = ((lm & 1) * 4 + quad) ^ ((lm >> 1) & 7);
  int aB = 8192 + prB * 64 + stb * 8;      // B frag j at aB + j*512

  f4_t accg[4][4], accu[4][4];
#pragma unroll
  for (int ii = 0; ii < 4; ++ii)
#pragma unroll
    for (int j = 0; j < 4; ++j)
#pragma unroll
      for (int r = 0; r < 4; ++r) { accg[ii][j][r] = 0.f; accu[ii][j][r] = 0.f; }

  auto stage = [&](int sb, int k) {
    glds16(pA + k,                &sm[sb + tid * 8]);
    glds16(pA + k + 32 * DMODEL,  &sm[sb + tid * 8 + 2048]);
    glds16(pA + k + 64 * DMODEL,  &sm[sb + tid * 8 + 4096]);
    glds16(pA + k + 96 * DMODEL,  &sm[sb + tid * 8 + 6144]);
    glds16(pB0 + k, &sm[sb + 8192 + tid * 8]);
    glds16(pB1 + k, &sm[sb + 8192 + tid * 8 + 2048]);
  };
  auto compute = [&](int sb) {
    bf16x8 b0 = *(const bf16x8*)&sm[sb + aB];
    bf16x8 b1 = *(const bf16x8*)&sm[sb + aB + 512];
    bf16x8 b2 = *(const bf16x8*)&sm[sb + aB + 1024];
    bf16x8 b3 = *(const bf16x8*)&sm[sb + aB + 1536];
#pragma unroll
    for (int ii = 0; ii < 4; ++ii) {
      bf16x8 ag = *(const bf16x8*)&sm[sb + aG + ii * 1024];
      bf16x8 au = *(const bf16x8*)&sm[sb + aU + ii * 1024];
      accg[ii][0] = MFMA16(ag, b0, accg[ii][0]);
      accg[ii][1] = MFMA16(ag, b1, accg[ii][1]);
      accg[ii][2] = MFMA16(ag, b2, accg[ii][2]);
      accg[ii][3] = MFMA16(ag, b3, accg[ii][3]);
      accu[ii][0] = MFMA16(au, b0, accu[ii][0]);
      accu[ii][1] = MFMA16(au, b1, accu[ii][1]);
      accu[ii][2] = MFMA16(au, b2, accu[ii][2]);
      accu[ii][3] = MFMA16(au, b3, accu[ii][3]);
    }
  };

#define G1_PHASE(CB, NB, KK)                               \
  stage(NB, KK);                                           \
  asm volatile("s_waitcnt vmcnt(6)" ::: "memory");         \
  __builtin_amdgcn_s_barrier();                            \
  asm volatile("" ::: "memory");                           \
  __builtin_amdgcn_s_setprio(1);                           \
  compute(CB);                                             \
  __builtin_amdgcn_s_setprio(0);

  stage(0, 0);
  int k = 0;
#pragma unroll 1
  for (int g = 0; g < 10; ++g) {
    G1_PHASE(0, 12288, k + 32);
    G1_PHASE(12288, 24576, k + 64);
    G1_PHASE(24576, 0, k + 96);
    k += 96;
  }
  G1_PHASE(0, 12288, 992);                 // phase 30
  asm volatile("s_waitcnt vmcnt(0)" ::: "memory");
  __builtin_amdgcn_s_barrier();
  asm volatile("" ::: "memory");
  __builtin_amdgcn_s_setprio(1);
  compute(12288);                          // phase 31
  __builtin_amdgcn_s_setprio(0);
#undef G1_PHASE

#pragma unroll
  for (int j = 0; j < 4; ++j) {
    int tok = wn * 64 + j * 16 + lm;
    if (tok < nvalid) {
      unsigned short* hrow = hbuf + (size_t)(h_base + tok) * DFFN + f0 + wm * 64 + quad * 4;
#pragma unroll
      for (int ii = 0; ii < 4; ++ii) {
        us4 h4;
#pragma unroll
        for (int r = 0; r < 4; ++r) {
          float g2 = accg[ii][j][r], u = accu[ii][j][r];
          h4[r] = f2bf(g2 / (1.f + __expf(-g2)) * u);
        }
        *(us4*)(hrow + ii * 16) = h4;
      }
    }
  }
}

// ---------------- G2: 4-wave 64x64 wave-tiles, 3-buffer counted-vmcnt down-proj ----------------
// per-buffer (shorts): A(tokens) [64 pr][64] = 4096, B(wd) [64 pr][64] = 4096.
__global__ __launch_bounds__(256, 3) void g2_kernel(
    const unsigned short* __restrict__ hbuf,
    const unsigned short* __restrict__ swdT, const unsigned short* __restrict__ ewdT,
    const int* __restrict__ counts, const int* __restrict__ offsets,
    const int* __restrict__ te, const int* __restrict__ tb, const int* __restrict__ ntl,
    const float* __restrict__ weight_list,
    float* __restrict__ out, float* __restrict__ eres) {
  // XCD chunking, d-fast within chunk (A-panel hot across 8 d-blocks)
  int bid = blockIdx.x;
  int b = (bid & 7) * (MT_ALL * 8 / 8) + (bid >> 3);
  int nt_blk = b & 7;
  int mt = b >> 3;
  int d0 = nt_blk * 128;
  const unsigned short* wdT;
  int h_base, tl_base, nvalid;
  bool shared_e;
  if (mt < MT_SH) {
    shared_e = true; wdT = swdT;
    h_base = mt * 128; tl_base = 0; nvalid = 128;
  } else {
    int em = mt - MT_SH;
    if (em >= ntl[0]) return;
    int e = te[em], lb = tb[em];
    shared_e = false;
    nvalid = min(128, counts[e] - lb);
    tl_base = offsets[e] + lb;
    h_base = TOKENS + tl_base;
    wdT = ewdT + (size_t)e * (DFFN * DMODEL);
  }
  __shared__ unsigned short sm[3 * 8192];
  __shared__ float s_w[128];
  int tid = threadIdx.x;
  if (tid < 128) {
    s_w[tid] = shared_e ? 1.f : weight_list[tl_base + min(tid, nvalid - 1)];
  }

  int rlo = tid >> 3;
  int c8 = (tid & 7) ^ (rlo & 7);
  int kc = (c8 & 3) * 8;
  int trow = rlo * 2 + (c8 >> 2);
  const unsigned short* pA = hbuf + (size_t)(h_base + trow) * DFFN + kc;
  const unsigned short* pB = wdT + (size_t)(d0 + trow) * DFFN + kc;

  int wv = tid >> 6, lane = tid & 63;
  int tq = wv & 1, dh = wv >> 1;           // token half, dmodel half
  int lm = lane & 15, quad = lane >> 4;

  int st = ((lm & 1) * 4 + quad) ^ ((lm >> 1) & 7);
  int aA = (tq * 32 + (lm >> 1)) * 64 + st * 8;           // A frag i at aA + i*512
  int aB = 4096 + (dh * 32 + (lm >> 1)) * 64 + st * 8;    // B frag j at aB + j*512

  f4_t acc[4][4];
#pragma unroll
  for (int ii = 0; ii < 4; ++ii)
#pragma unroll
    for (int j = 0; j < 4; ++j)
#pragma unroll
      for (int r = 0; r < 4; ++r) acc[ii][j][r] = 0.f;

  auto stage = [&](int sb, int k) {
    glds16(pA + k,             &sm[sb + tid * 8]);
    glds16(pA + k + 64 * DFFN, &sm[sb + tid * 8 + 2048]);
    glds16(pB + k,             &sm[sb + 4096 + tid * 8]);
    glds16(pB + k + 64 * DFFN, &sm[sb + 4096 + tid * 8 + 2048]);
  };
  auto compute = [&](int sb) {
    bf16x8 b0 = *(const bf16x8*)&sm[sb + aB];
    bf16x8 b1 = *(const bf16x8*)&sm[sb + aB + 512];
    bf16x8 b2 = *(const bf16x8*)&sm[sb + aB + 1024];
    bf16x8 b3 = *(const bf16x8*)&sm[sb + aB + 1536];
#pragma unroll
    for (int ii = 0; ii < 4; ++ii) {
      bf16x8 a = *(const bf16x8*)&sm[sb + aA + ii * 512];
      acc[ii][0] = MFMA16(a, b0, acc[ii][0]);
      acc[ii][1] = MFMA16(a, b1, acc[ii][1]);
      acc[ii][2] = MFMA16(a, b2, acc[ii][2]);
      acc[ii][3] = MFMA16(a, b3, acc[ii][3]);
    }
  };

#define G2_PHASE(CB, NB, KK)                               \
  stage(NB, KK);                                           \
  asm volatile("s_waitcnt vmcnt(4)" ::: "memory");         \
  __builtin_amdgcn_s_barrier();                            \
  asm volatile("" ::: "memory");                           \
  __builtin_amdgcn_s_setprio(1);                           \
  compute(CB);                                             \
  __builtin_amdgcn_s_setprio(0);

  stage(0, 0);
  int k = 0;
#pragma unroll 1
  for (int g = 0; g < 21; ++g) {           // phases 0..62
    G2_PHASE(0, 8192, k + 32);
    G2_PHASE(8192, 16384, k + 64);
    G2_PHASE(16384, 0, k + 96);
    k += 96;
  }
  asm volatile("s_waitcnt vmcnt(0)" ::: "memory");
  __builtin_amdgcn_s_barrier();
  asm volatile("" ::: "memory");
  __builtin_amdgcn_s_setprio(1);
  compute(0);                              // phase 63
  __builtin_amdgcn_s_setprio(0);
#undef G2_PHASE

#pragma unroll
  for (int ii = 0; ii < 4; ++ii)
#pragma unroll
    for (int r = 0; r < 4; ++r) {
      int rw = tq * 64 + ii * 16 + quad * 4 + r;
      if (rw < nvalid) {
        float w = s_w[rw];
        if (shared_e) {
          float* orow = out + (size_t)(h_base + rw) * DMODEL + d0 + dh * 64 + lm;
          orow[0]  = acc[ii][0][r];
          orow[16] = acc[ii][1][r];
          orow[32] = acc[ii][2][r];
          orow[48] = acc[ii][3][r];
        } else {
          float* erow = eres + (size_t)(tl_base + rw) * DMODEL + d0 + dh * 64 + lm;
          erow[0]  = w * acc[ii][0][r];
          erow[16] = w * acc[ii][1][r];
          erow[32] = w * acc[ii][2][r];
          erow[48] = w * acc[ii][3][r];
        }
      }
    }
}

// ---------------- combine ----------------
__global__ __launch_bounds__(256) void combine_kernel(float* __restrict__ out,
                                                      const float* __restrict__ eres,
                                                      const int* __restrict__ slot_idx) {
  int t = blockIdx.x;
  int s1 = slot_idx[2 * t], s2 = slot_idx[2 * t + 1];
  int d = threadIdx.x * 4;
  float4 o = *(float4*)&out[(size_t)t * DMODEL + d];
  float4 a = *(const float4*)&eres[(size_t)s1 * DMODEL + d];
  float4 b = *(const float4*)&eres[(size_t)s2 * DMODEL + d];
  o.x += a.x + b.x; o.y += a.y + b.y; o.z += a.z + b.z; o.w += a.w + b.w;
  *(float4*)&out[(size_t)t * DMODEL + d] = o;
}

extern "C" void kernel_launch(void* const* d_in, const int* in_sizes, int n_in,
                              void* d_out, int out_size, void* d_ws, size_t ws_size,
                              hipStream_t stream) {
  const float* x   = (const float*)d_in[0];
  const float* swg = (const float*)d_in[1];
  const float* swu = (const float*)d_in[2];
  const float* swd = (const float*)d_in[3];
  const float* ewg = (const float*)d_in[4];
  const float* ewu = (const float*)d_in[5];
  const float* ewd = (const float*)d_in[6];
  const float* rw  = (const float*)d_in[7];
  float* out = (float*)d_out;

  char* ws = (char*)d_ws;
  const size_t MB = 1048576;
  int*   fill     = (int*)(ws + 0);
  int*   counts   = (int*)(ws + 64);
  int*   offsets  = (int*)(ws + 128);
  int*   ntl      = (int*)(ws + 192);
  int*   te       = (int*)(ws + 256);
  int*   tb       = (int*)(ws + 1024);
  int*   topi     = (int*)(ws + 65536);
  float* topw     = (float*)(ws + 98304);
  int*   c_part   = (int*)(ws + 131072);
  float* p_part   = (float*)(ws + 163840);
  int*   tok_list = (int*)(ws + 196608);
  float* w_list   = (float*)(ws + 229376);
  int*   slot_idx = (int*)(ws + 262144);
  unsigned short* xb   = (unsigned short*)(ws + 1 * MB);
  unsigned short* swgT = (unsigned short*)(ws + 16 * MB);
  unsigned short* swuT = (unsigned short*)(ws + 20 * MB);
  unsigned short* swdT = (unsigned short*)(ws + 24 * MB);
  unsigned short* ewgT = (unsigned short*)(ws + 28 * MB);
  unsigned short* ewuT = (unsigned short*)(ws + 60 * MB);
  unsigned short* ewdT = (unsigned short*)(ws + 92 * MB);
  float*          eres = (float*)(ws + 28 * MB);
  unsigned short* hbuf = (unsigned short*)(ws + 124 * MB);

  hipMemsetAsync(ws, 0, 32, stream);  // fill[]

  prepass_kernel<<<CONV_BLKS + 6912, 256, 0, stream>>>(
      x, xb, swg, swgT, swu, swuT, swd, swdT, ewg, ewgT, ewu, ewuT, ewd, ewdT);
  router_kernel<<<TOKENS / 4, 256, 0, stream>>>(x, rw, topi, topw, c_part, p_part);
  scan_aux_kernel<<<1, 256, 0, stream>>>(c_part, p_part, counts, offsets, te, tb, ntl,
                                         out + (size_t)TOKENS * DMODEL);
  dispatch_kernel<<<TOKENS / 256, 256, 0, stream>>>(topi, topw, offsets, fill,
                                                    tok_list, w_list, slot_idx);

  g1_kernel<<<MT_ALL * 16, 256, 0, stream>>>(xb, swgT, swuT, ewgT, ewuT,
                                             counts, offsets, te, tb, ntl, tok_list, hbuf);
  g2_kernel<<<MT_ALL * 8, 256, 0, stream>>>(hbuf, swdT, ewdT,
                                            counts, offsets, te, tb, ntl, w_list, out, eres);
  combine_kernel<<<TOKENS, 256, 0, stream>>>(out, eres, slot_idx);
}